// Round 7
// baseline (690.574 us; speedup 1.0000x reference)
//
#include <hip/hip_runtime.h>
#include <hip/hip_bf16.h>

using bf16 = __hip_bfloat16;
typedef __attribute__((ext_vector_type(8))) short bf16x8;
typedef __attribute__((ext_vector_type(4))) float f32x4;
typedef __attribute__((ext_vector_type(4))) int i32x4;

#define DECAY 0.25f

// ---------------------------------------------------------------- helpers
__device__ __forceinline__ void gload_lds16(const void* g, void* l) {
  __builtin_amdgcn_global_load_lds(
      (const __attribute__((address_space(1))) void*)g,
      (__attribute__((address_space(3))) void*)l, 16, 0, 0);
}

#define CFENCE() asm volatile("" ::: "memory")
#define VMCNT4() asm volatile("s_waitcnt vmcnt(4)" ::: "memory")

__device__ __forceinline__ unsigned short f2bf(float f) {
  __hip_bfloat16 h = __float2bfloat16(f);
  return *reinterpret_cast<unsigned short*>(&h);
}

// ---------------------------------------------------------------- prep kernels
__global__ void cast_x_k(const float4* __restrict__ x, ushort4* __restrict__ xb, int n4) {
  int i = blockIdx.x * blockDim.x + threadIdx.x;
  int stride = gridDim.x * blockDim.x;
  for (; i < n4; i += stride) {
    float4 v = x[i];
    ushort4 o;
    o.x = f2bf(v.x); o.y = f2bf(v.y); o.z = f2bf(v.z); o.w = f2bf(v.w);
    xb[i] = o;
  }
}

__global__ void transpose_cast_k(const float* __restrict__ w, bf16* __restrict__ wt, int N) {
  __shared__ float t[32][33];
  int bx = blockIdx.x * 32, by = blockIdx.y * 32;
  int tx = threadIdx.x, ty = threadIdx.y;  // block (32,8)
#pragma unroll
  for (int i = 0; i < 32; i += 8)
    t[ty + i][tx] = w[(size_t)(by + ty + i) * N + bx + tx];
  __syncthreads();
#pragma unroll
  for (int i = 0; i < 32; i += 8)
    wt[(size_t)(bx + ty + i) * N + by + tx] = __float2bfloat16(t[tx][ty + i]);
}

// per-output-column (n) absmax of w_out[k][n] -> scale (mx/127) and inv (127/mx)
__global__ void colmax_k(const float* __restrict__ w, float* __restrict__ scale,
                         float* __restrict__ inv, int K, int N) {
  int n = blockIdx.x * blockDim.x + threadIdx.x;
  float mx = 0.f;
  for (int k = 0; k < K; ++k) mx = fmaxf(mx, fabsf(w[(size_t)k * N + n]));
  scale[n] = mx * (1.f / 127.f);
  inv[n] = 127.f / mx;
}

// w_out [K][N] f32 -> w_q8T [N][K] i8, per-n scaling
__global__ void transpose_quant_k(const float* __restrict__ w, const float* __restrict__ inv,
                                  signed char* __restrict__ wq, int N, int K) {
  __shared__ float t[32][33];
  int bx = blockIdx.x * 32, by = blockIdx.y * 32;  // bx: n-range, by: k-range
  int tx = threadIdx.x, ty = threadIdx.y;          // block (32,8)
#pragma unroll
  for (int i = 0; i < 32; i += 8)
    t[ty + i][tx] = w[(size_t)(by + ty + i) * N + bx + tx];
  __syncthreads();
#pragma unroll
  for (int i = 0; i < 32; i += 8) {
    int n = bx + ty + i;
    float v = t[tx][ty + i] * inv[n];
    int q = __float2int_rn(v);
    q = max(-127, min(127, q));
    wq[(size_t)n * K + by + tx] = (signed char)q;
  }
}

// ---------------------------------------------------------------- GEMM1: bf16 256x256 (R6 body, plain 2-D grid)
// FRAGMENT-MAJOR planes: plane byte d = f*1024 + l*16 holds
// src[row0+f*16+(l&15)][k0+(l>>4)*8 ..+8]; 0 bank conflicts (verified R3).
__device__ __forceinline__ void stage_plane(const bf16* __restrict__ src, int ldk,
                                            int row0, int k0, char* plane, int tid) {
#pragma unroll
  for (int u = 0; u < 2; ++u) {
    int d = tid * 16 + u * 8192;
    int f = d >> 10;
    int l = (d >> 4) & 63;
    const bf16* g = src + (size_t)(row0 + f * 16 + (l & 15)) * ldk + k0 + (l >> 4) * 8;
    gload_lds16(g, plane + d);
  }
}

__device__ __forceinline__ void mfma16(const bf16x8 (&a)[4], const bf16x8 (&b)[4],
                                       f32x4 (&acc)[8][4], int mh) {
#pragma unroll
  for (int i = 0; i < 4; ++i)
#pragma unroll
    for (int j = 0; j < 4; ++j)
      acc[mh * 4 + i][j] =
          __builtin_amdgcn_mfma_f32_16x16x32_bf16(a[i], b[j], acc[mh * 4 + i][j], 0, 0, 0);
}

__global__ __launch_bounds__(512, 1) void gemm1_bf16_k(
    const bf16* __restrict__ A, const bf16* __restrict__ BT,
    bf16* __restrict__ C, const float* __restrict__ bias, int M, int N, int K) {
  __shared__ char lds[131072];
  const int tid = threadIdx.x;
  const int lane = tid & 63;
  const int w = tid >> 6;
  const int wr = w >> 2, wc = w & 3;  // 2M x 4N waves, per-wave 128x64 out
  const int tm = blockIdx.x * 256, tn = blockIdx.y * 256;
  const int ro = lane * 16;
  const int NT = K >> 6;

  f32x4 acc[8][4] = {};

  stage_plane(A,  K, tm, 0,  lds + 0,     tid);
  stage_plane(BT, K, tn, 0,  lds + 32768, tid);
  stage_plane(A,  K, tm, 32, lds + 16384, tid);
  stage_plane(BT, K, tn, 32, lds + 49152, tid);
  CFENCE();
  VMCNT4();
  __builtin_amdgcn_s_barrier();

  for (int t = 0; t < NT; ++t) {
    const char* cb = lds + (t & 1) * 65536;
    char* nb = lds + ((t + 1) & 1) * 65536;
    const int k1 = (t + 1 < NT ? t + 1 : NT - 1) * 64;
    const char* pa = cb + wr * 8192;
    const char* pb = cb + 32768 + wc * 4096;
    bf16x8 a[4], b[4];

    // p0 (kl, mh0); stage A_kl(t+1)
    stage_plane(A, K, tm, k1, nb + 0, tid);
#pragma unroll
    for (int j = 0; j < 4; ++j) b[j] = *(const bf16x8*)(pb + j * 1024 + ro);
#pragma unroll
    for (int i = 0; i < 4; ++i) a[i] = *(const bf16x8*)(pa + i * 1024 + ro);
    __builtin_amdgcn_s_setprio(1);
    mfma16(a, b, acc, 0);
    __builtin_amdgcn_s_setprio(0);
    CFENCE();
    __builtin_amdgcn_s_barrier();

    // p1 (kl, mh1); stage B_kl(t+1)
    stage_plane(BT, K, tn, k1, nb + 32768, tid);
#pragma unroll
    for (int i = 0; i < 4; ++i) a[i] = *(const bf16x8*)(pa + 4096 + i * 1024 + ro);
    __builtin_amdgcn_s_setprio(1);
    mfma16(a, b, acc, 1);
    __builtin_amdgcn_s_setprio(0);
    CFENCE();
    VMCNT4();
    __builtin_amdgcn_s_barrier();

    // p2 (kr, mh0); stage A_kr(t+1)
    stage_plane(A, K, tm, k1 + 32, nb + 16384, tid);
#pragma unroll
    for (int j = 0; j < 4; ++j) b[j] = *(const bf16x8*)(pb + 16384 + j * 1024 + ro);
#pragma unroll
    for (int i = 0; i < 4; ++i) a[i] = *(const bf16x8*)(pa + 16384 + i * 1024 + ro);
    __builtin_amdgcn_s_setprio(1);
    mfma16(a, b, acc, 0);
    __builtin_amdgcn_s_setprio(0);
    CFENCE();
    __builtin_amdgcn_s_barrier();

    // p3 (kr, mh1); stage B_kr(t+1)
    stage_plane(BT, K, tn, k1 + 32, nb + 49152, tid);
#pragma unroll
    for (int i = 0; i < 4; ++i) a[i] = *(const bf16x8*)(pa + 16384 + 4096 + i * 1024 + ro);
    __builtin_amdgcn_s_setprio(1);
    mfma16(a, b, acc, 1);
    __builtin_amdgcn_s_setprio(0);
    CFENCE();
    VMCNT4();
    __builtin_amdgcn_s_barrier();
  }

  // epilogue: C/D layout col=lane&15, row=(lane>>4)*4+r  [m89]
#pragma unroll
  for (int i = 0; i < 8; ++i) {
    int m0 = tm + wr * 128 + i * 16 + (lane >> 4) * 4;
#pragma unroll
    for (int j = 0; j < 4; ++j) {
      int n = tn + wc * 64 + j * 16 + (lane & 15);
      float bb = bias[n];
#pragma unroll
      for (int r = 0; r < 4; ++r)
        C[(size_t)(m0 + r) * N + n] = __float2bfloat16(acc[i][j][r] + bb);
    }
  }
}

// ---------------------------------------------------------------- GEMM2: i8 256x256, 2 phases/tile, 3-buffer ring
// A = spikes [M][K] u8 (values 0..4), BT = w_q8T [N][K] i8.
// i8 FRAGMENT-MAJOR plane (16KB covers 256 rows x 64 k):
//   byte d = f*1024 + l*16 holds src[row0+f*16+(l&15)][k0+(l>>4)*16 ..+16]
// Ring r at r*32768: A@+0, B@+16384. Stage t+2 during t; vmcnt(4) at end-p1
// drains t+1's planes (ledger: outstanding = {t+1:4, t+2:4} per thread).
__device__ __forceinline__ void stage_plane_i8(const signed char* __restrict__ src, int ldk,
                                               int row0, int k0, char* plane, int tid) {
#pragma unroll
  for (int u = 0; u < 2; ++u) {
    int d = tid * 16 + u * 8192;
    int f = d >> 10;
    int l = (d >> 4) & 63;
    const signed char* g = src + (size_t)(row0 + f * 16 + (l & 15)) * ldk + k0 + (l >> 4) * 16;
    gload_lds16(g, plane + d);
  }
}

__global__ __launch_bounds__(512, 1) void gemm2_i8_k(
    const signed char* __restrict__ A, const signed char* __restrict__ BT,
    float* __restrict__ C, const float* __restrict__ scale,
    const float* __restrict__ bias, const float* __restrict__ xres,
    const float* __restrict__ alpha_p, int M, int N, int K) {
  __shared__ char lds[98304];
  const int tid = threadIdx.x;
  const int lane = tid & 63;
  const int w = tid >> 6;
  const int wr = w >> 2, wc = w & 3;  // 2M x 4N waves, per-wave 128x64 out
  const int tm = blockIdx.x * 256, tn = blockIdx.y * 256;
  const int ro = lane * 16;
  const int NT = K >> 6;

  i32x4 acc[8][4] = {};

  // prologue: tiles 0 and 1 staged (8 loads/thread); vmcnt(4): tile0 landed
  stage_plane_i8(A,  K, tm, 0,  lds + 0,     tid);
  stage_plane_i8(BT, K, tn, 0,  lds + 16384, tid);
  stage_plane_i8(A,  K, tm, 64, lds + 32768, tid);
  stage_plane_i8(BT, K, tn, 64, lds + 49152, tid);
  CFENCE();
  VMCNT4();
  __builtin_amdgcn_s_barrier();

  for (int t = 0; t < NT; ++t) {
    const char* cb = lds + (t % 3) * 32768;
    char* sb = lds + ((t + 2) % 3) * 32768;
    const int k2 = (t + 2 < NT ? t + 2 : NT - 1) * 64;
    const char* pa = cb + wr * 8192;
    const char* pb = cb + 16384 + wc * 4096;
    i32x4 a[4], b[4];

    // p0 (mh0); stage A(t+2)
    stage_plane_i8(A, K, tm, k2, sb + 0, tid);
#pragma unroll
    for (int j = 0; j < 4; ++j) b[j] = *(const i32x4*)(pb + j * 1024 + ro);
#pragma unroll
    for (int i = 0; i < 4; ++i) a[i] = *(const i32x4*)(pa + i * 1024 + ro);
    __builtin_amdgcn_s_setprio(1);
#pragma unroll
    for (int i = 0; i < 4; ++i)
#pragma unroll
      for (int j = 0; j < 4; ++j)
        acc[i][j] = __builtin_amdgcn_mfma_i32_16x16x64_i8(a[i], b[j], acc[i][j], 0, 0, 0);
    __builtin_amdgcn_s_setprio(0);
    CFENCE();
    __builtin_amdgcn_s_barrier();

    // p1 (mh1); stage B(t+2)
    stage_plane_i8(BT, K, tn, k2, sb + 16384, tid);
#pragma unroll
    for (int i = 0; i < 4; ++i) a[i] = *(const i32x4*)(pa + 4096 + i * 1024 + ro);
    __builtin_amdgcn_s_setprio(1);
#pragma unroll
    for (int i = 0; i < 4; ++i)
#pragma unroll
      for (int j = 0; j < 4; ++j)
        acc[4 + i][j] = __builtin_amdgcn_mfma_i32_16x16x64_i8(a[i], b[j], acc[4 + i][j], 0, 0, 0);
    __builtin_amdgcn_s_setprio(0);
    CFENCE();
    VMCNT4();  // t+1's 4 plane-loads landed; t+2's 4 in flight
    __builtin_amdgcn_s_barrier();
  }

  // epilogue: out = x + alpha*(acc*scale[n] + b_out[n]); C/D layout as [m89]
  float alpha = *alpha_p;
#pragma unroll
  for (int i = 0; i < 8; ++i) {
    int m0 = tm + wr * 128 + i * 16 + (lane >> 4) * 4;
#pragma unroll
    for (int j = 0; j < 4; ++j) {
      int n = tn + wc * 64 + j * 16 + (lane & 15);
      float sc = scale[n];
      float bb = bias[n];
#pragma unroll
      for (int r = 0; r < 4; ++r) {
        size_t idx = (size_t)(m0 + r) * N + n;
        C[idx] = xres[idx] + alpha * ((float)acc[i][j][r] * sc + bb);
      }
    }
  }
}

// ---------------------------------------------------------------- chunked LIF scan (bf16 in, u8 out)
__global__ void snn_scan_k(const bf16* __restrict__ xp, unsigned char* __restrict__ sp,
                           const float* __restrict__ thre_p,
                           int T, int H, int CHUNK, int WARM) {
  int h = blockIdx.x * blockDim.x + threadIdx.x;
  int b = blockIdx.y;
  int c = blockIdx.z;
  float thre = *thre_p;
  float l1 = thre, l2 = 2.f * thre, l3 = 3.f * thre, l4 = 4.f * thre;
  int t0 = c * CHUNK;
  int tw = t0 - WARM;
  if (tw < 0) tw = 0;
  const bf16* xcol = xp + (size_t)b * T * H + h;
  unsigned char* scol = sp + (size_t)b * T * H + h;
  float mem = 0.f;
  for (int t = tw; t < t0; ++t) {  // warmup (state error ~0.25^WARM)
    float xv = __bfloat162float(xcol[(size_t)t * H]);
    mem = DECAY * mem + xv;
    int s = (mem >= l1) + (mem >= l2) + (mem >= l3) + (mem >= l4);
    mem -= (float)s * thre;
  }
  for (int t = t0; t < t0 + CHUNK; ++t) {
    float xv = __bfloat162float(xcol[(size_t)t * H]);
    mem = DECAY * mem + xv;
    int s = (mem >= l1) + (mem >= l2) + (mem >= l3) + (mem >= l4);
    mem -= (float)s * thre;
    scol[(size_t)t * H] = (unsigned char)s;
  }
}

// ---------------------------------------------------------------- launch
extern "C" void kernel_launch(void* const* d_in, const int* in_sizes, int n_in,
                              void* d_out, int out_size, void* d_ws, size_t ws_size,
                              hipStream_t stream) {
  const float* x     = (const float*)d_in[0];
  const float* alpha = (const float*)d_in[1];
  const float* thre  = (const float*)d_in[2];
  const float* w_in  = (const float*)d_in[3];
  const float* b_in  = (const float*)d_in[4];
  const float* w_out = (const float*)d_in[5];
  const float* b_out = (const float*)d_in[6];
  float* out = (float*)d_out;

  const int B = 4, T = 2048, H = 2048;
  const int M = B * T;  // 8192
  const int K = H, N = H;

  char* ws = (char*)d_ws;
  size_t off = 0;
  bf16* xb            = (bf16*)(ws + off);                       // 33.5MB
  signed char* spikes = (signed char*)(ws + off);                // alias: xb dead after GEMM1
  off += (size_t)M * K * 2;
  bf16* w_inT  = (bf16*)(ws + off);        off += (size_t)K * N * 2;   // 8.4MB
  signed char* w_q8T = (signed char*)(ws + off); off += (size_t)K * N; // 4.2MB
  float* qscale = (float*)(ws + off);      off += (size_t)N * 4;
  float* qinv   = (float*)(ws + off);      off += (size_t)N * 4;
  bf16* xp      = (bf16*)(ws + off);       off += (size_t)M * K * 2;   // 33.5MB

  cast_x_k<<<2048, 256, 0, stream>>>((const float4*)x, (ushort4*)xb, M * K / 4);
  dim3 tb(32, 8);
  dim3 tg(N / 32, K / 32);
  transpose_cast_k<<<tg, tb, 0, stream>>>(w_in, w_inT, N);
  colmax_k<<<N / 256, 256, 0, stream>>>(w_out, qscale, qinv, K, N);
  transpose_quant_k<<<tg, tb, 0, stream>>>(w_out, qinv, w_q8T, N, K);

  dim3 gg(M / 256, N / 256);
  gemm1_bf16_k<<<gg, 512, 0, stream>>>(xb, w_inT, xp, b_in, M, N, K);

  const int CHUNK = 128, WARM = 32, NC = T / CHUNK;
  dim3 sg(H / 256, B, NC);
  snn_scan_k<<<sg, 256, 0, stream>>>(xp, (unsigned char*)spikes, thre, T, H, CHUNK, WARM);

  gemm2_i8_k<<<gg, 512, 0, stream>>>(spikes, w_q8T, out, qscale, b_out, x, alpha, M, N, K);
}

// Round 8
// 237.948 us; speedup vs baseline: 2.9022x; 2.9022x over previous
//
#include <hip/hip_runtime.h>
#include <hip/hip_bf16.h>

using bf16 = __hip_bfloat16;
typedef __attribute__((ext_vector_type(8))) short bf16x8;
typedef __attribute__((ext_vector_type(4))) float f32x4;
typedef __attribute__((ext_vector_type(4))) int i32x4;

#define DECAY 0.25f

// ---------------------------------------------------------------- helpers
__device__ __forceinline__ void gload_lds16(const void* g, void* l) {
  __builtin_amdgcn_global_load_lds(
      (const __attribute__((address_space(1))) void*)g,
      (__attribute__((address_space(3))) void*)l, 16, 0, 0);
}

#define CFENCE() asm volatile("" ::: "memory")
#define VMCNT4() asm volatile("s_waitcnt vmcnt(4)" ::: "memory")

__device__ __forceinline__ unsigned short f2bf(float f) {
  __hip_bfloat16 h = __float2bfloat16(f);
  return *reinterpret_cast<unsigned short*>(&h);
}

// ---------------------------------------------------------------- prep kernels
__global__ void cast_x_k(const float4* __restrict__ x, ushort4* __restrict__ xb, int n4) {
  int i = blockIdx.x * blockDim.x + threadIdx.x;
  int stride = gridDim.x * blockDim.x;
  for (; i < n4; i += stride) {
    float4 v = x[i];
    ushort4 o;
    o.x = f2bf(v.x); o.y = f2bf(v.y); o.z = f2bf(v.z); o.w = f2bf(v.w);
    xb[i] = o;
  }
}

__global__ void transpose_cast_k(const float* __restrict__ w, bf16* __restrict__ wt, int N) {
  __shared__ float t[32][33];
  int bx = blockIdx.x * 32, by = blockIdx.y * 32;
  int tx = threadIdx.x, ty = threadIdx.y;  // block (32,8)
#pragma unroll
  for (int i = 0; i < 32; i += 8)
    t[ty + i][tx] = w[(size_t)(by + ty + i) * N + bx + tx];
  __syncthreads();
#pragma unroll
  for (int i = 0; i < 32; i += 8)
    wt[(size_t)(bx + ty + i) * N + by + tx] = __float2bfloat16(t[tx][ty + i]);
}

// stage 1: per-(k-slab, n) partial absmax, coalesced reads, atomicMax on uint bits
// (valid: absmax >= 0, and non-negative IEEE f32 orders identically to its bits)
__global__ void colmax_part_k(const float* __restrict__ w, unsigned int* __restrict__ maxbits,
                              int N, int KCH) {
  int n = blockIdx.x * blockDim.x + threadIdx.x;
  int k0 = blockIdx.y * KCH;
  float mx = 0.f;
  for (int k = k0; k < k0 + KCH; ++k) mx = fmaxf(mx, fabsf(w[(size_t)k * N + n]));
  atomicMax(&maxbits[n], __float_as_uint(mx));
}

// stage 2: scale = mx/127, inv = 127/mx
__global__ void colmax_fin_k(const unsigned int* __restrict__ maxbits,
                             float* __restrict__ scale, float* __restrict__ inv, int N) {
  int n = blockIdx.x * blockDim.x + threadIdx.x;
  float mx = __uint_as_float(maxbits[n]);
  scale[n] = mx * (1.f / 127.f);
  inv[n] = (mx > 0.f) ? 127.f / mx : 0.f;
}

// w_out [K][N] f32 -> w_q8T [N][K] i8, per-n scaling
__global__ void transpose_quant_k(const float* __restrict__ w, const float* __restrict__ inv,
                                  signed char* __restrict__ wq, int N, int K) {
  __shared__ float t[32][33];
  int bx = blockIdx.x * 32, by = blockIdx.y * 32;  // bx: n-range, by: k-range
  int tx = threadIdx.x, ty = threadIdx.y;          // block (32,8)
#pragma unroll
  for (int i = 0; i < 32; i += 8)
    t[ty + i][tx] = w[(size_t)(by + ty + i) * N + bx + tx];
  __syncthreads();
#pragma unroll
  for (int i = 0; i < 32; i += 8) {
    int n = bx + ty + i;
    float v = t[tx][ty + i] * inv[n];
    int q = __float2int_rn(v);
    q = max(-127, min(127, q));
    wq[(size_t)n * K + by + tx] = (signed char)q;
  }
}

// ---------------------------------------------------------------- GEMM1: bf16 256x256 (R6 body, plain 2-D grid)
// FRAGMENT-MAJOR planes: plane byte d = f*1024 + l*16 holds
// src[row0+f*16+(l&15)][k0+(l>>4)*8 ..+8]; 0 bank conflicts (verified R3).
__device__ __forceinline__ void stage_plane(const bf16* __restrict__ src, int ldk,
                                            int row0, int k0, char* plane, int tid) {
#pragma unroll
  for (int u = 0; u < 2; ++u) {
    int d = tid * 16 + u * 8192;
    int f = d >> 10;
    int l = (d >> 4) & 63;
    const bf16* g = src + (size_t)(row0 + f * 16 + (l & 15)) * ldk + k0 + (l >> 4) * 8;
    gload_lds16(g, plane + d);
  }
}

__device__ __forceinline__ void mfma16(const bf16x8 (&a)[4], const bf16x8 (&b)[4],
                                       f32x4 (&acc)[8][4], int mh) {
#pragma unroll
  for (int i = 0; i < 4; ++i)
#pragma unroll
    for (int j = 0; j < 4; ++j)
      acc[mh * 4 + i][j] =
          __builtin_amdgcn_mfma_f32_16x16x32_bf16(a[i], b[j], acc[mh * 4 + i][j], 0, 0, 0);
}

__global__ __launch_bounds__(512, 1) void gemm1_bf16_k(
    const bf16* __restrict__ A, const bf16* __restrict__ BT,
    bf16* __restrict__ C, const float* __restrict__ bias, int M, int N, int K) {
  __shared__ char lds[131072];
  const int tid = threadIdx.x;
  const int lane = tid & 63;
  const int w = tid >> 6;
  const int wr = w >> 2, wc = w & 3;  // 2M x 4N waves, per-wave 128x64 out
  const int tm = blockIdx.x * 256, tn = blockIdx.y * 256;
  const int ro = lane * 16;
  const int NT = K >> 6;

  f32x4 acc[8][4] = {};

  stage_plane(A,  K, tm, 0,  lds + 0,     tid);
  stage_plane(BT, K, tn, 0,  lds + 32768, tid);
  stage_plane(A,  K, tm, 32, lds + 16384, tid);
  stage_plane(BT, K, tn, 32, lds + 49152, tid);
  CFENCE();
  VMCNT4();
  __builtin_amdgcn_s_barrier();

  for (int t = 0; t < NT; ++t) {
    const char* cb = lds + (t & 1) * 65536;
    char* nb = lds + ((t + 1) & 1) * 65536;
    const int k1 = (t + 1 < NT ? t + 1 : NT - 1) * 64;
    const char* pa = cb + wr * 8192;
    const char* pb = cb + 32768 + wc * 4096;
    bf16x8 a[4], b[4];

    // p0 (kl, mh0); stage A_kl(t+1)
    stage_plane(A, K, tm, k1, nb + 0, tid);
#pragma unroll
    for (int j = 0; j < 4; ++j) b[j] = *(const bf16x8*)(pb + j * 1024 + ro);
#pragma unroll
    for (int i = 0; i < 4; ++i) a[i] = *(const bf16x8*)(pa + i * 1024 + ro);
    __builtin_amdgcn_s_setprio(1);
    mfma16(a, b, acc, 0);
    __builtin_amdgcn_s_setprio(0);
    CFENCE();
    __builtin_amdgcn_s_barrier();

    // p1 (kl, mh1); stage B_kl(t+1)
    stage_plane(BT, K, tn, k1, nb + 32768, tid);
#pragma unroll
    for (int i = 0; i < 4; ++i) a[i] = *(const bf16x8*)(pa + 4096 + i * 1024 + ro);
    __builtin_amdgcn_s_setprio(1);
    mfma16(a, b, acc, 1);
    __builtin_amdgcn_s_setprio(0);
    CFENCE();
    VMCNT4();
    __builtin_amdgcn_s_barrier();

    // p2 (kr, mh0); stage A_kr(t+1)
    stage_plane(A, K, tm, k1 + 32, nb + 16384, tid);
#pragma unroll
    for (int j = 0; j < 4; ++j) b[j] = *(const bf16x8*)(pb + 16384 + j * 1024 + ro);
#pragma unroll
    for (int i = 0; i < 4; ++i) a[i] = *(const bf16x8*)(pa + 16384 + i * 1024 + ro);
    __builtin_amdgcn_s_setprio(1);
    mfma16(a, b, acc, 0);
    __builtin_amdgcn_s_setprio(0);
    CFENCE();
    __builtin_amdgcn_s_barrier();

    // p3 (kr, mh1); stage B_kr(t+1)
    stage_plane(BT, K, tn, k1 + 32, nb + 49152, tid);
#pragma unroll
    for (int i = 0; i < 4; ++i) a[i] = *(const bf16x8*)(pa + 16384 + 4096 + i * 1024 + ro);
    __builtin_amdgcn_s_setprio(1);
    mfma16(a, b, acc, 1);
    __builtin_amdgcn_s_setprio(0);
    CFENCE();
    VMCNT4();
    __builtin_amdgcn_s_barrier();
  }

  // epilogue: C/D layout col=lane&15, row=(lane>>4)*4+r  [m89]
#pragma unroll
  for (int i = 0; i < 8; ++i) {
    int m0 = tm + wr * 128 + i * 16 + (lane >> 4) * 4;
#pragma unroll
    for (int j = 0; j < 4; ++j) {
      int n = tn + wc * 64 + j * 16 + (lane & 15);
      float bb = bias[n];
#pragma unroll
      for (int r = 0; r < 4; ++r)
        C[(size_t)(m0 + r) * N + n] = __float2bfloat16(acc[i][j][r] + bb);
    }
  }
}

// ---------------------------------------------------------------- GEMM2: i8 256x256, 2 phases/tile, 3-buffer ring
// A = spikes [M][K] u8 (values 0..4), BT = w_q8T [N][K] i8.
// i8 FRAGMENT-MAJOR plane (16KB covers 256 rows x 64 k):
//   byte d = f*1024 + l*16 holds src[row0+f*16+(l&15)][k0+(l>>4)*16 ..+16]
// Ring r at r*32768: A@+0, B@+16384. Stage t+2 during t; vmcnt(4) at end-p1
// drains t+1's planes (ledger: outstanding = {t+1:4, t+2:4} per thread).
__device__ __forceinline__ void stage_plane_i8(const signed char* __restrict__ src, int ldk,
                                               int row0, int k0, char* plane, int tid) {
#pragma unroll
  for (int u = 0; u < 2; ++u) {
    int d = tid * 16 + u * 8192;
    int f = d >> 10;
    int l = (d >> 4) & 63;
    const signed char* g = src + (size_t)(row0 + f * 16 + (l & 15)) * ldk + k0 + (l >> 4) * 16;
    gload_lds16(g, plane + d);
  }
}

__global__ __launch_bounds__(512, 1) void gemm2_i8_k(
    const signed char* __restrict__ A, const signed char* __restrict__ BT,
    float* __restrict__ C, const float* __restrict__ scale,
    const float* __restrict__ bias, const float* __restrict__ xres,
    const float* __restrict__ alpha_p, int M, int N, int K) {
  __shared__ char lds[98304];
  const int tid = threadIdx.x;
  const int lane = tid & 63;
  const int w = tid >> 6;
  const int wr = w >> 2, wc = w & 3;  // 2M x 4N waves, per-wave 128x64 out
  const int tm = blockIdx.x * 256, tn = blockIdx.y * 256;
  const int ro = lane * 16;
  const int NT = K >> 6;

  i32x4 acc[8][4] = {};

  // prologue: tiles 0 and 1 staged (8 loads/thread); vmcnt(4): tile0 landed
  stage_plane_i8(A,  K, tm, 0,  lds + 0,     tid);
  stage_plane_i8(BT, K, tn, 0,  lds + 16384, tid);
  stage_plane_i8(A,  K, tm, 64, lds + 32768, tid);
  stage_plane_i8(BT, K, tn, 64, lds + 49152, tid);
  CFENCE();
  VMCNT4();
  __builtin_amdgcn_s_barrier();

  for (int t = 0; t < NT; ++t) {
    const char* cb = lds + (t % 3) * 32768;
    char* sb = lds + ((t + 2) % 3) * 32768;
    const int k2 = (t + 2 < NT ? t + 2 : NT - 1) * 64;
    const char* pa = cb + wr * 8192;
    const char* pb = cb + 16384 + wc * 4096;
    i32x4 a[4], b[4];

    // p0 (mh0); stage A(t+2)
    stage_plane_i8(A, K, tm, k2, sb + 0, tid);
#pragma unroll
    for (int j = 0; j < 4; ++j) b[j] = *(const i32x4*)(pb + j * 1024 + ro);
#pragma unroll
    for (int i = 0; i < 4; ++i) a[i] = *(const i32x4*)(pa + i * 1024 + ro);
    __builtin_amdgcn_s_setprio(1);
#pragma unroll
    for (int i = 0; i < 4; ++i)
#pragma unroll
      for (int j = 0; j < 4; ++j)
        acc[i][j] = __builtin_amdgcn_mfma_i32_16x16x64_i8(a[i], b[j], acc[i][j], 0, 0, 0);
    __builtin_amdgcn_s_setprio(0);
    CFENCE();
    __builtin_amdgcn_s_barrier();

    // p1 (mh1); stage B(t+2)
    stage_plane_i8(BT, K, tn, k2, sb + 16384, tid);
#pragma unroll
    for (int i = 0; i < 4; ++i) a[i] = *(const i32x4*)(pa + 4096 + i * 1024 + ro);
    __builtin_amdgcn_s_setprio(1);
#pragma unroll
    for (int i = 0; i < 4; ++i)
#pragma unroll
      for (int j = 0; j < 4; ++j)
        acc[4 + i][j] = __builtin_amdgcn_mfma_i32_16x16x64_i8(a[i], b[j], acc[4 + i][j], 0, 0, 0);
    __builtin_amdgcn_s_setprio(0);
    CFENCE();
    VMCNT4();  // t+1's 4 plane-loads landed; t+2's 4 in flight
    __builtin_amdgcn_s_barrier();
  }

  // epilogue: out = x + alpha*(acc*scale[n] + b_out[n]); C/D layout as [m89]
  float alpha = *alpha_p;
#pragma unroll
  for (int i = 0; i < 8; ++i) {
    int m0 = tm + wr * 128 + i * 16 + (lane >> 4) * 4;
#pragma unroll
    for (int j = 0; j < 4; ++j) {
      int n = tn + wc * 64 + j * 16 + (lane & 15);
      float sc = scale[n];
      float bb = bias[n];
#pragma unroll
      for (int r = 0; r < 4; ++r) {
        size_t idx = (size_t)(m0 + r) * N + n;
        C[idx] = xres[idx] + alpha * ((float)acc[i][j][r] * sc + bb);
      }
    }
  }
}

// ---------------------------------------------------------------- chunked LIF scan (bf16 in, u8 out)
__global__ void snn_scan_k(const bf16* __restrict__ xp, unsigned char* __restrict__ sp,
                           const float* __restrict__ thre_p,
                           int T, int H, int CHUNK, int WARM) {
  int h = blockIdx.x * blockDim.x + threadIdx.x;
  int b = blockIdx.y;
  int c = blockIdx.z;
  float thre = *thre_p;
  float l1 = thre, l2 = 2.f * thre, l3 = 3.f * thre, l4 = 4.f * thre;
  int t0 = c * CHUNK;
  int tw = t0 - WARM;
  if (tw < 0) tw = 0;
  const bf16* xcol = xp + (size_t)b * T * H + h;
  unsigned char* scol = sp + (size_t)b * T * H + h;
  float mem = 0.f;
  for (int t = tw; t < t0; ++t) {  // warmup (state error ~0.25^WARM)
    float xv = __bfloat162float(xcol[(size_t)t * H]);
    mem = DECAY * mem + xv;
    int s = (mem >= l1) + (mem >= l2) + (mem >= l3) + (mem >= l4);
    mem -= (float)s * thre;
  }
  for (int t = t0; t < t0 + CHUNK; ++t) {
    float xv = __bfloat162float(xcol[(size_t)t * H]);
    mem = DECAY * mem + xv;
    int s = (mem >= l1) + (mem >= l2) + (mem >= l3) + (mem >= l4);
    mem -= (float)s * thre;
    scol[(size_t)t * H] = (unsigned char)s;
  }
}

// ---------------------------------------------------------------- launch
extern "C" void kernel_launch(void* const* d_in, const int* in_sizes, int n_in,
                              void* d_out, int out_size, void* d_ws, size_t ws_size,
                              hipStream_t stream) {
  const float* x     = (const float*)d_in[0];
  const float* alpha = (const float*)d_in[1];
  const float* thre  = (const float*)d_in[2];
  const float* w_in  = (const float*)d_in[3];
  const float* b_in  = (const float*)d_in[4];
  const float* w_out = (const float*)d_in[5];
  const float* b_out = (const float*)d_in[6];
  float* out = (float*)d_out;

  const int B = 4, T = 2048, H = 2048;
  const int M = B * T;  // 8192
  const int K = H, N = H;

  char* ws = (char*)d_ws;
  size_t off = 0;
  bf16* xb            = (bf16*)(ws + off);                       // 33.5MB
  signed char* spikes = (signed char*)(ws + off);                // alias: xb dead after GEMM1
  off += (size_t)M * K * 2;
  bf16* w_inT  = (bf16*)(ws + off);        off += (size_t)K * N * 2;   // 8.4MB
  signed char* w_q8T = (signed char*)(ws + off); off += (size_t)K * N; // 4.2MB
  float* qscale = (float*)(ws + off);      off += (size_t)N * 4;
  float* qinv   = (float*)(ws + off);      off += (size_t)N * 4;
  unsigned int* qmaxbits = (unsigned int*)(ws + off); off += (size_t)N * 4;
  bf16* xp      = (bf16*)(ws + off);       off += (size_t)M * K * 2;   // 33.5MB

  cast_x_k<<<2048, 256, 0, stream>>>((const float4*)x, (ushort4*)xb, M * K / 4);
  dim3 tb(32, 8);
  dim3 tg(N / 32, K / 32);
  transpose_cast_k<<<tg, tb, 0, stream>>>(w_in, w_inT, N);

  // two-stage coalesced column-absmax (fixes R7's 810us serial colmax)
  hipMemsetAsync(qmaxbits, 0, (size_t)N * 4, stream);
  const int KCH = 128;
  dim3 cg(N / 256, K / KCH);
  colmax_part_k<<<cg, 256, 0, stream>>>(w_out, qmaxbits, N, KCH);
  colmax_fin_k<<<N / 256, 256, 0, stream>>>(qmaxbits, qscale, qinv, N);
  transpose_quant_k<<<tg, tb, 0, stream>>>(w_out, qinv, w_q8T, N, K);

  dim3 gg(M / 256, N / 256);
  gemm1_bf16_k<<<gg, 512, 0, stream>>>(xb, w_inT, xp, b_in, M, N, K);

  const int CHUNK = 128, WARM = 32, NC = T / CHUNK;
  dim3 sg(H / 256, B, NC);
  snn_scan_k<<<sg, 256, 0, stream>>>(xp, (unsigned char*)spikes, thre, T, H, CHUNK, WARM);

  gemm2_i8_k<<<gg, 512, 0, stream>>>(spikes, w_q8T, out, qscale, b_out, x, alpha, M, N, K);
}